// Round 8
// baseline (148.299 us; speedup 1.0000x reference)
//
#include <hip/hip_runtime.h>
#include <stdint.h>

#define HID 128
#define BPB 16  // batch elements (waves) per block; block = 1024 threads

// Full-wave64 f32 sum via DPP (VALU pipe, no LDS). Totals land in lane 63.
__device__ __forceinline__ void wave_reduce_add2(float& a, float& b) {
  asm("v_add_f32 %0, %0, %0 row_shr:1 bound_ctrl:0\n\t"
      "v_add_f32 %1, %1, %1 row_shr:1 bound_ctrl:0\n\t"
      "v_add_f32 %0, %0, %0 row_shr:2 bound_ctrl:0\n\t"
      "v_add_f32 %1, %1, %1 row_shr:2 bound_ctrl:0\n\t"
      "v_add_f32 %0, %0, %0 row_shr:4 bound_ctrl:0\n\t"
      "v_add_f32 %1, %1, %1 row_shr:4 bound_ctrl:0\n\t"
      "v_add_f32 %0, %0, %0 row_shr:8 bound_ctrl:0\n\t"
      "v_add_f32 %1, %1, %1 row_shr:8 bound_ctrl:0\n\t"
      "v_add_f32 %0, %0, %0 row_bcast:15 row_mask:0xa\n\t"
      "v_add_f32 %1, %1, %1 row_bcast:15 row_mask:0xa\n\t"
      "v_add_f32 %0, %0, %0 row_bcast:31 row_mask:0xc\n\t"
      "v_add_f32 %1, %1, %1 row_bcast:31 row_mask:0xc\n\t"
      : "+v"(a), "+v"(b));
}

__global__ __launch_bounds__(1024, 4) void lsnn_fwd(
    const float* __restrict__ x,      // (B,4)
    const float* __restrict__ w_in,   // (128,8)
    const float* __restrict__ w_rec,  // (128,128)
    const float* __restrict__ w_out,  // (2,128)
    float* __restrict__ out,          // (B,2)
    int B)
{
#pragma clang fp contract(off)
  // Transposed recurrent weights: wt[k][l'] = (w_rec[l][k], w_rec[l+64][k])
  // with l' = l ^ (k & 63). Per spiking k (uniform), lanes read contiguous
  // (permuted) float2 -> conflict-free ds_read_b64. 64 KiB.
  __shared__ float2 wt[HID * 64];

  const int tid = threadIdx.x;
#pragma unroll
  for (int m = 0; m < 8; ++m) {
    int idx = m * 1024 + tid;
    int k = idx & 127;        // presynaptic index (coalesced fast axis)
    int l = idx >> 7;         // postsynaptic pair index 0..63
    float a = w_rec[l * HID + k];
    float c = w_rec[(l + 64) * HID + k];
    wt[(k << 6) | (l ^ (k & 63))] = make_float2(a, c);
  }
  __syncthreads();

  const int lane = tid & 63;
  const int b = blockIdx.x * BPB + (tid >> 6);
  if (b >= B) return;

  const int j0 = lane;
  const int j1 = lane + 64;

  // ---------- encoder: 4 effective channels (pos/neg mutually exclusive) ---
  float cc[4], ev[4];
  float wsel0[4], wsel1[4];
  {
#pragma unroll
    for (int c = 0; c < 4; ++c) {
      float p = 50.0f * x[b * 4 + c];
      cc[c] = fabsf(p);
      ev[c] = 0.0f;
      int col = (p > 0.0f) ? c : (c + 4);
      wsel0[c] = w_in[j0 * 8 + col];
      wsel1[c] = w_in[j1 * 8 + col];
    }
  }

  // 40 steps x 4 channel-bits, one byte per step, 8 steps per 64-bit word.
  // Encoder state is identical across the wave's lanes -> hoist the packed
  // words into SGPRs so per-step gating is pure SALU (uniform branches).
  uint64_t spkw[5];
#pragma unroll
  for (int tw = 0; tw < 5; ++tw) {
    uint32_t lo = 0, hi = 0;
    for (int ts = 0; ts < 8; ++ts) {
      unsigned byte = 0;
#pragma unroll
      for (int c = 0; c < 4; ++c) {
        ev[c] = ev[c] + 0.1f * (cc[c] - ev[c]);
        if (ev[c] - 1.0f > 0.0f) {
          byte |= (1u << c);
          ev[c] = 0.0f;
        }
      }
      if (ts < 4) lo |= byte << (ts << 3);
      else        hi |= byte << ((ts - 4) << 3);
    }
    uint32_t slo = (uint32_t)__builtin_amdgcn_readfirstlane((int)lo);
    uint32_t shi = (uint32_t)__builtin_amdgcn_readfirstlane((int)hi);
    spkw[tw] = ((uint64_t)shi << 32) | slo;
  }

  const float wo00 = w_out[j0], wo01 = w_out[j1];
  const float wo10 = w_out[HID + j0], wo11 = w_out[HID + j1];

  // ---------- state ----------
  float v0 = 0.f, v1 = 0.f, i0 = 0.f, i1 = 0.f, b0 = 1.0f, b1 = 1.0f;
  float io0 = 0.f, io1 = 0.f, vo0 = 0.f, vo1 = 0.f;
  float mm0 = -INFINITY, mm1 = -INFINITY;
  uint64_t zm0 = 0ull, zm1 = 0ull;

  const char* wtb = (const char*)wt;
  const int vb = lane << 3;  // per-lane float2 byte base; XOR'ed with k-offset

  // ---------- T=40 recurrent steps (5 words x 8 steps) ----------
#pragma unroll
  for (int tw = 0; tw < 5; ++tw) {
    uint64_t cw = spkw[tw];  // SGPR pair; low nibble of each byte = step
    for (int ts = 0; ts < 8; ++ts) {
      const unsigned xb = (unsigned)(cw & 0xFull);  // scalar, uniform
      cw >>= 8;

      // recurrent current from PREVIOUS step's z, hoisted to the top so the
      // LDS reads overlap the independent state-update / DPP VALU work.
      // One conflict-free ds_read_b64 per spiking k, ascending k
      // (reference accumulation order preserved -> bit-exact).
      float ar0 = 0.f, ar1 = 0.f;
      uint64_t m0 = zm0;
      while (m0) {
        int k = __builtin_ctzll(m0);
        m0 &= m0 - 1;
        int soff = k * 520;  // (k<<9)|(k<<3), disjoint bit fields
        float2 w = *(const float2*)(wtb + (vb ^ soff));
        ar0 += w.x;
        ar1 += w.y;
      }
      uint64_t m1 = zm1;
      while (m1) {
        int k = __builtin_ctzll(m1);
        m1 &= m1 - 1;
        int soff = 32768 + k * 520;  // ((64+k)<<9)|(k<<3)
        float2 w = *(const float2*)(wtb + (vb ^ soff));
        ar0 += w.x;
        ar1 += w.y;
      }

      // ---- membrane / adaptation state update (bit-exact path) ----
      float vd0 = v0 + 0.1f * (i0 - v0);
      float vd1 = v1 + 0.1f * (i1 - v1);
      float id0 = i0 - 0.2f * i0;
      float id1 = i1 - 0.2f * i1;
      float bd0 = b0 + 1.4285714285714286e-06f * (1.0f - b0);
      float bd1 = b1 + 1.4285714285714286e-06f * (1.0f - b1);
      bool z0 = (vd0 - bd0) > 0.0f;
      bool z1 = (vd1 - bd1) > 0.0f;

      // ballots immediately after the compares: the next iteration's gather
      // depends only on these, so it can issue under this step's DPP blob.
      zm0 = __ballot(z0);
      zm1 = __ballot(z1);

      v0 = z0 ? 0.0f : vd0;
      v1 = z1 ? 0.0f : vd1;
      b0 = bd0 + (z0 ? 0.0025714285714285714f : 0.0f);
      b1 = bd1 + (z1 ? 0.0025714285714285714f : 0.0f);

      // input current from encoder spikes (xb is SGPR -> uniform branches)
      float ai0 = 0.f, ai1 = 0.f;
      if (xb & 1u) { ai0 += wsel0[0]; ai1 += wsel1[0]; }
      if (xb & 2u) { ai0 += wsel0[1]; ai1 += wsel1[1]; }
      if (xb & 4u) { ai0 += wsel0[2]; ai1 += wsel1[2]; }
      if (xb & 8u) { ai0 += wsel0[3]; ai1 += wsel1[3]; }

      i0 = (id0 + ai0) + ar0;
      i1 = (id1 + ai1) + ar1;

      // readout projection of z_new: DPP wave-reduce (valid in lane 63 only)
      float p0 = (z0 ? wo00 : 0.0f) + (z1 ? wo01 : 0.0f);
      float p1 = (z0 ? wo10 : 0.0f) + (z1 ? wo11 : 0.0f);
      wave_reduce_add2(p0, p1);

      // LI readout (vo uses OLD io), fma-form (readout path: no feedback
      // into spikes, so fused rounding is safe). Valid in lane 63 only.
      float von0 = __builtin_fmaf(0.1f, io0, 0.9f * vo0);
      float von1 = __builtin_fmaf(0.1f, io1, 0.9f * vo1);
      io0 = __builtin_fmaf(0.8f, io0, p0);
      io1 = __builtin_fmaf(0.8f, io1, p1);
      vo0 = von0;
      vo1 = von1;
      mm0 = fmaxf(mm0, von0);
      mm1 = fmaxf(mm1, von1);
    }
  }

  // ---------- softmax over the 2 per-batch max-voltages (lane 63 valid) ----
  if (lane == 63) {
    float mx = fmaxf(mm0, mm1);
    float e0 = expf(mm0 - mx);
    float e1 = expf(mm1 - mx);
    float s = e0 + e1;
    out[b * 2 + 0] = e0 / s;
    out[b * 2 + 1] = e1 / s;
  }
}

extern "C" void kernel_launch(void* const* d_in, const int* in_sizes, int n_in,
                              void* d_out, int out_size, void* d_ws, size_t ws_size,
                              hipStream_t stream) {
  (void)n_in; (void)out_size; (void)d_ws; (void)ws_size;
  const float* x = (const float*)d_in[0];
  const float* w_in = (const float*)d_in[1];
  const float* w_rec = (const float*)d_in[2];
  const float* w_out = (const float*)d_in[3];
  float* out = (float*)d_out;
  int B = in_sizes[0] / 4;
  int blocks = (B + BPB - 1) / BPB;
  lsnn_fwd<<<blocks, 1024, 0, stream>>>(x, w_in, w_rec, w_out, out, B);
}

// Round 9
// 142.950 us; speedup vs baseline: 1.0374x; 1.0374x over previous
//
#include <hip/hip_runtime.h>
#include <stdint.h>

#define HID 128
#define BPB 16  // batch elements (waves) per block; block = 1024 threads

// Full-wave64 f32 sum via DPP (VALU pipe, no LDS). Totals land in lane 63.
__device__ __forceinline__ void wave_reduce_add2(float& a, float& b) {
  asm("v_add_f32 %0, %0, %0 row_shr:1 bound_ctrl:0\n\t"
      "v_add_f32 %1, %1, %1 row_shr:1 bound_ctrl:0\n\t"
      "v_add_f32 %0, %0, %0 row_shr:2 bound_ctrl:0\n\t"
      "v_add_f32 %1, %1, %1 row_shr:2 bound_ctrl:0\n\t"
      "v_add_f32 %0, %0, %0 row_shr:4 bound_ctrl:0\n\t"
      "v_add_f32 %1, %1, %1 row_shr:4 bound_ctrl:0\n\t"
      "v_add_f32 %0, %0, %0 row_shr:8 bound_ctrl:0\n\t"
      "v_add_f32 %1, %1, %1 row_shr:8 bound_ctrl:0\n\t"
      "v_add_f32 %0, %0, %0 row_bcast:15 row_mask:0xa\n\t"
      "v_add_f32 %1, %1, %1 row_bcast:15 row_mask:0xa\n\t"
      "v_add_f32 %0, %0, %0 row_bcast:31 row_mask:0xc\n\t"
      "v_add_f32 %1, %1, %1 row_bcast:31 row_mask:0xc\n\t"
      : "+v"(a), "+v"(b));
}

__global__ __launch_bounds__(1024, 4) void lsnn_fwd(
    const float* __restrict__ x,      // (B,4)
    const float* __restrict__ w_in,   // (128,8)
    const float* __restrict__ w_rec,  // (128,128)
    const float* __restrict__ w_out,  // (2,128)
    float* __restrict__ out,          // (B,2)
    int B)
{
#pragma clang fp contract(off)
  // Transposed recurrent weights: wt[k][l'] = (w_rec[l][k], w_rec[l+64][k])
  // with l' = l ^ (k & 63). Per spiking k (uniform), lanes read contiguous
  // (permuted) float2 -> conflict-free ds_read_b64. 64 KiB.
  __shared__ float2 wt[HID * 64];

  const int tid = threadIdx.x;
#pragma unroll
  for (int m = 0; m < 8; ++m) {
    int idx = m * 1024 + tid;
    int k = idx & 127;        // presynaptic index (coalesced fast axis)
    int l = idx >> 7;         // postsynaptic pair index 0..63
    float a = w_rec[l * HID + k];
    float c = w_rec[(l + 64) * HID + k];
    wt[(k << 6) | (l ^ (k & 63))] = make_float2(a, c);
  }
  __syncthreads();

  const int lane = tid & 63;
  const int b = blockIdx.x * BPB + (tid >> 6);
  if (b >= B) return;

  const int j0 = lane;
  const int j1 = lane + 64;

  // ---------- encoder: 4 effective channels (pos/neg mutually exclusive) ---
  float cc[4], ev[4];
  float wsel0[4], wsel1[4];
  {
#pragma unroll
    for (int c = 0; c < 4; ++c) {
      float p = 50.0f * x[b * 4 + c];
      cc[c] = fabsf(p);
      ev[c] = 0.0f;
      int col = (p > 0.0f) ? c : (c + 4);
      wsel0[c] = w_in[j0 * 8 + col];
      wsel1[c] = w_in[j1 * 8 + col];
    }
  }

  uint64_t pk[5];  // 40 steps x 4 channel-bits, one byte per step
#pragma unroll
  for (int tw = 0; tw < 5; ++tw) {
    uint64_t pw = 0;
    for (int ts = 0; ts < 8; ++ts) {
      unsigned byte = 0;
#pragma unroll
      for (int c = 0; c < 4; ++c) {
        ev[c] = ev[c] + 0.1f * (cc[c] - ev[c]);
        if (ev[c] - 1.0f > 0.0f) {
          byte |= (1u << c);
          ev[c] = 0.0f;
        }
      }
      pw |= ((uint64_t)byte) << (ts << 3);
    }
    pk[tw] = pw;
  }

  const float wo00 = w_out[j0], wo01 = w_out[j1];
  const float wo10 = w_out[HID + j0], wo11 = w_out[HID + j1];

  // ---------- state ----------
  float v0 = 0.f, v1 = 0.f, i0 = 0.f, i1 = 0.f, b0 = 1.0f, b1 = 1.0f;
  float io0 = 0.f, io1 = 0.f, vo0 = 0.f, vo1 = 0.f;
  float mm0 = -INFINITY, mm1 = -INFINITY;
  uint64_t zm0 = 0ull, zm1 = 0ull;

  const char* wtb = (const char*)wt;
  const int vb = lane << 3;  // per-lane float2 byte base; XOR'ed with k-offset

  // ---------- T=40 recurrent steps (5 words x 8 steps, static pk index) ----
#pragma unroll
  for (int tw = 0; tw < 5; ++tw) {
    uint64_t pw = pk[tw];
    for (int ts = 0; ts < 8; ++ts) {
      // recurrent current from PREVIOUS step's z, hoisted to the top so the
      // LDS reads overlap the independent state-update / DPP VALU work.
      // One conflict-free ds_read_b64 per spiking k, ascending k
      // (reference accumulation order preserved -> bit-exact).
      float ar0 = 0.f, ar1 = 0.f;
      uint64_t m0 = zm0;
      while (m0) {
        int k = __builtin_ctzll(m0);
        m0 &= m0 - 1;
        int soff = k * 520;  // (k<<9)|(k<<3), disjoint bit fields
        float2 w = *(const float2*)(wtb + (vb ^ soff));
        ar0 += w.x;
        ar1 += w.y;
      }
      uint64_t m1 = zm1;
      while (m1) {
        int k = __builtin_ctzll(m1);
        m1 &= m1 - 1;
        int soff = 32768 + k * 520;  // ((64+k)<<9)|(k<<3)
        float2 w = *(const float2*)(wtb + (vb ^ soff));
        ar0 += w.x;
        ar1 += w.y;
      }

      // ---- membrane / adaptation state update (bit-exact path) ----
      float vd0 = v0 + 0.1f * (i0 - v0);
      float vd1 = v1 + 0.1f * (i1 - v1);
      float id0 = i0 - 0.2f * i0;
      float id1 = i1 - 0.2f * i1;
      float bd0 = b0 + 1.4285714285714286e-06f * (1.0f - b0);
      float bd1 = b1 + 1.4285714285714286e-06f * (1.0f - b1);
      bool z0 = (vd0 - bd0) > 0.0f;
      bool z1 = (vd1 - bd1) > 0.0f;
      v0 = z0 ? 0.0f : vd0;
      v1 = z1 ? 0.0f : vd1;
      b0 = bd0 + (z0 ? 0.0025714285714285714f : 0.0f);
      b1 = bd1 + (z1 ? 0.0025714285714285714f : 0.0f);

      // readout projection of z_new: DPP wave-reduce (valid in lane 63 only)
      float p0 = (z0 ? wo00 : 0.0f) + (z1 ? wo01 : 0.0f);
      float p1 = (z0 ? wo10 : 0.0f) + (z1 ? wo11 : 0.0f);
      wave_reduce_add2(p0, p1);

      // LI readout (vo uses OLD io), fma-form (readout path: no feedback
      // into spikes, so fused rounding is safe). Valid in lane 63 only.
      float von0 = __builtin_fmaf(0.1f, io0, 0.9f * vo0);
      float von1 = __builtin_fmaf(0.1f, io1, 0.9f * vo1);
      io0 = __builtin_fmaf(0.8f, io0, p0);
      io1 = __builtin_fmaf(0.8f, io1, p1);
      vo0 = von0;
      vo1 = von1;
      mm0 = fmaxf(mm0, von0);
      mm1 = fmaxf(mm1, von1);

      // input current from encoder spikes (nibble identical across lanes)
      int xb = (int)((pw >> (ts << 3)) & 0xFF);
      float ai0 = 0.f, ai1 = 0.f;
#pragma unroll
      for (int c = 0; c < 4; ++c) {
        if (xb & (1 << c)) {
          ai0 += wsel0[c];
          ai1 += wsel1[c];
        }
      }

      i0 = (id0 + ai0) + ar0;
      i1 = (id1 + ai1) + ar1;

      zm0 = __ballot(z0);
      zm1 = __ballot(z1);
    }
  }

  // ---------- softmax over the 2 per-batch max-voltages (lane 63 valid) ----
  if (lane == 63) {
    float mx = fmaxf(mm0, mm1);
    float e0 = expf(mm0 - mx);
    float e1 = expf(mm1 - mx);
    float s = e0 + e1;
    out[b * 2 + 0] = e0 / s;
    out[b * 2 + 1] = e1 / s;
  }
}

extern "C" void kernel_launch(void* const* d_in, const int* in_sizes, int n_in,
                              void* d_out, int out_size, void* d_ws, size_t ws_size,
                              hipStream_t stream) {
  (void)n_in; (void)out_size; (void)d_ws; (void)ws_size;
  const float* x = (const float*)d_in[0];
  const float* w_in = (const float*)d_in[1];
  const float* w_rec = (const float*)d_in[2];
  const float* w_out = (const float*)d_in[3];
  float* out = (float*)d_out;
  int B = in_sizes[0] / 4;
  int blocks = (B + BPB - 1) / BPB;
  lsnn_fwd<<<blocks, 1024, 0, stream>>>(x, w_in, w_rec, w_out, out, B);
}